// Round 9
// baseline (380.211 us; speedup 1.0000x reference)
//
#include <hip/hip_runtime.h>

typedef short bf16x8 __attribute__((ext_vector_type(8)));
typedef float f32x4 __attribute__((ext_vector_type(4)));

#define MFMA16(a, b, c) __builtin_amdgcn_mfma_f32_16x16x32_bf16(a, b, c, 0, 0, 0)

__device__ __forceinline__ short f2bf(float f) {
  unsigned u = __builtin_bit_cast(unsigned, f);
  u += 0x7fffu + ((u >> 16) & 1u);   // round-to-nearest-even
  return (short)(u >> 16);
}

// async global->LDS, 16B per lane; LDS dest is wave-uniform base (+ lane*16 by HW)
__device__ __forceinline__ void gload16(const void* g, void* l) {
  __builtin_amdgcn_global_load_lds(
      (const __attribute__((address_space(1))) void*)g,
      (__attribute__((address_space(3))) void*)l, 16, 0, 0);
}

// Problem sizes (fixed)
// B=4, N=2048, D=512, H=8, DH=64, M = B*N = 8192, 3*H*DH = 1536
#define L2E 1.44269504088896f

// ---------------- K0: merged prep (cvt + both weight transposes) ----------------

__device__ __forceinline__ void transpose_body(const float* __restrict__ in,
                                               short* __restrict__ out,
                                               int K, int N, int bx, int by,
                                               short (*Ts)[72], int t) {
  const int k0 = by * 64, n1 = bx * 64;
  const int kk = t >> 2, nq = (t & 3) * 16;
  const float* src = in + (size_t)(k0 + kk) * N + n1 + nq;
#pragma unroll
  for (int i = 0; i < 16; ++i) Ts[nq + i][kk] = f2bf(src[i]);
  __syncthreads();
  const int n = t >> 2, kq = (t & 3) * 16;
  short* dst = out + (size_t)(n1 + n) * K + k0 + kq;
  *(bf16x8*)dst = *(const bf16x8*)&Ts[n][kq];
  *(bf16x8*)(dst + 8) = *(const bf16x8*)&Ts[n][kq + 8];
}

__global__ __launch_bounds__(256) void prep(const float* __restrict__ x,
                                            const float* __restrict__ w_qkv,
                                            const float* __restrict__ w_out,
                                            short* __restrict__ xbf,
                                            short* __restrict__ wqkvT,
                                            short* __restrict__ woutT) {
  __shared__ short Ts[64][72];
  const int bid = blockIdx.x, t = threadIdx.x;
  if (bid < 2048) {
    size_t i = ((size_t)bid * 256 + t) * 8;
    const float4* p = (const float4*)(x + i);
    float4 a = p[0], b = p[1];
    bf16x8 v;
    v[0] = f2bf(a.x); v[1] = f2bf(a.y); v[2] = f2bf(a.z); v[3] = f2bf(a.w);
    v[4] = f2bf(b.x); v[5] = f2bf(b.y); v[6] = f2bf(b.z); v[7] = f2bf(b.w);
    *(bf16x8*)(xbf + i) = v;
  } else if (bid < 2240) {
    const int sub = bid - 2048;
    transpose_body(w_qkv, wqkvT, 512, 1536, sub % 24, sub / 24, Ts, t);
  } else {
    const int sub = bid - 2240;
    transpose_body(w_out, woutT, 512, 512, sub % 8, sub / 8, Ts, t);
  }
}

// ---------------- shared async GEMM mainloop: C[128x128] tile, K=512 ----------------
// (verified R7/R8 version)

__device__ __forceinline__ void gemm128_async(const short* __restrict__ A,
                                              const short* __restrict__ BT,
                                              int m0, int n0,
                                              char* As, char* Bs,
                                              f32x4 acc[4][4]) {
  const int t = threadIdx.x;
  const int w = t >> 6, lane = t & 63, l15 = lane & 15, quad = lane >> 4;
  const int wm = (w & 1) * 64, wn = (w >> 1) * 64;
  const int scol = ((lane & 3) ^ ((lane >> 3) & 3)) << 4;
  const char* ag = (const char*)A + (size_t)(m0 + w * 32 + (lane >> 2)) * 1024 + scol;
  const char* bg = (const char*)BT + (size_t)(n0 + w * 32 + (lane >> 2)) * 1024 + scol;
  char* al = As + w * 2048;
  char* bl = Bs + w * 2048;
  const int rsw = (quad ^ ((l15 >> 1) & 3)) << 4;
  const int ra = (wm + l15) * 64 + rsw;
  const int rb = (wn + l15) * 64 + rsw;

#define GQ_STAGE(BUF, KB)                                                      \
  do {                                                                         \
    gload16(ag + (KB), al + (BUF) * 8192);                                     \
    gload16(ag + 16384 + (KB), al + (BUF) * 8192 + 1024);                      \
    gload16(bg + (KB), bl + (BUF) * 8192);                                     \
    gload16(bg + 16384 + (KB), bl + (BUF) * 8192 + 1024);                      \
  } while (0)

  GQ_STAGE(0, 0);
  __syncthreads();
#pragma unroll 2
  for (int s = 0; s < 16; ++s) {
    const int buf = s & 1;
    if (s < 15) GQ_STAGE(buf ^ 1, (s + 1) * 64);
    bf16x8 af[4], bfr[4];
#pragma unroll
    for (int i = 0; i < 4; ++i)
      af[i] = *(const bf16x8*)(As + buf * 8192 + ra + i * 1024);
#pragma unroll
    for (int j = 0; j < 4; ++j)
      bfr[j] = *(const bf16x8*)(Bs + buf * 8192 + rb + j * 1024);
#pragma unroll
    for (int i = 0; i < 4; ++i)
#pragma unroll
      for (int j = 0; j < 4; ++j)
        acc[i][j] = MFMA16(af[i], bfr[j], acc[i][j]);
    __syncthreads();
  }
#undef GQ_STAGE
}

// ---------------- K1: QKV projection ----------------
// v6 epilogue: q/k no longer use 48 scattered scalar b16 stores per thread
// (25 MB of uncoalesced writes).  Like the v path, each 64-row half of the
// C tile is staged as bf16 in Ts, then 256 threads emit contiguous 64B
// (4x b128) coalesced stores.  Output layout [bh][seq][64] is row-contiguous
// per head; a 128-col tile covers exactly 2 heads (hA, hA+1).

__global__ __launch_bounds__(256) void gemm_qkv(const short* __restrict__ A,
                                                const short* __restrict__ BT,
                                                short* __restrict__ q_ws,
                                                short* __restrict__ k_ws,
                                                short* __restrict__ v_t) {
  __shared__ short As[2][128][32];
  __shared__ short Bs[2][128][32];
  __shared__ short Ts[64][136];
  const int t = threadIdx.x;
  const int w = t >> 6, lane = t & 63, l15 = lane & 15, quad = lane >> 4;
  const int wm = (w & 1) * 64, wn = (w >> 1) * 64;
  const int m0 = blockIdx.y * 128, n0 = blockIdx.x * 128;
  f32x4 acc[4][4];
#pragma unroll
  for (int i = 0; i < 4; ++i)
#pragma unroll
    for (int j = 0; j < 4; ++j) acc[i][j] = (f32x4){0.f, 0.f, 0.f, 0.f};

  gemm128_async(A, BT, m0, n0, (char*)&As[0][0][0], (char*)&Bs[0][0][0], acc);

  const int which = n0 >> 9;            // 0=q 1=k 2=v
  const int b = m0 >> 11, seq0 = m0 & 2047;
  if (which < 2) {
    short* dst = (which == 0) ? q_ws : k_ws;
    const float scale = (which == 0) ? (0.125f * L2E) : 1.0f;
    const int hA = (n0 >> 6) & 7;
    for (int half = 0; half < 2; ++half) {     // row-half of the 128-row tile
      __syncthreads();
      if ((w & 1) == half) {                   // waves whose wm == half*64
#pragma unroll
        for (int i = 0; i < 4; ++i)
#pragma unroll
          for (int j = 0; j < 4; ++j)
#pragma unroll
            for (int r = 0; r < 4; ++r)
              Ts[i * 16 + quad * 4 + r][wn + j * 16 + l15] =
                  f2bf(acc[i][j][r] * scale);
      }
      __syncthreads();
      // coalesced copy-out: thread t -> row ro, 32-col group cg (64B)
      const int ro = t >> 2, cg = t & 3;
      short* dstp = dst +
          ((size_t)(b * 8 + hA + (cg >> 1)) * 2048 + seq0 + half * 64 + ro) * 64 +
          (cg & 1) * 32;
      const short* srcp = &Ts[ro][cg * 32];
#pragma unroll
      for (int u = 0; u < 4; ++u)
        *(bf16x8*)(dstp + u * 8) = *(const bf16x8*)(srcp + u * 8);
    }
  } else {
    for (int half = 0; half < 2; ++half) {
      __syncthreads();
      if ((w >> 1) == half) {
#pragma unroll
        for (int i = 0; i < 4; ++i)
#pragma unroll
          for (int j = 0; j < 4; ++j)
#pragma unroll
            for (int r = 0; r < 4; ++r)
              Ts[j * 16 + l15][wm + i * 16 + quad * 4 + r] = f2bf(acc[i][j][r]);
      }
      __syncthreads();
      const int hd = ((n0 + half * 64) >> 6) & 7;
      const int dp = t >> 2, sq = (t & 3) * 32;
      short* dstp = v_t + ((size_t)(b * 8 + hd) * 64 + dp) * 2048 + seq0 + sq;
#pragma unroll
      for (int u = 0; u < 4; ++u)
        *(bf16x8*)(dstp + u * 8) = *(const bf16x8*)&Ts[dp][sq + u * 8];
    }
  }
}

// ---------------- K2: fused flash attention (no-max softmax) ----------------
// v6 = R8 structure (counted-vmcnt barrier, XCD-pinned grid, K/V LDS dbuf via
// global_load_lds, swizzled; P via Pw; bias ping-pong register prefetch) with
// ONE change: T5 s_setprio(1/0) around both MFMA clusters (guide m191:
// +4-7% on attn with independent blocks per CU at different phases).

#define ATTN_STAGE(BUFD, J0N)                                                  \
  do {                                                                         \
    _Pragma("unroll") for (int i_ = 0; i_ < 2; ++i_) {                         \
      const int ch_ = w * 2 + i_;                                              \
      const int off_ = ch_ * 1024 + lane * 16;                                 \
      const int row_ = off_ >> 7;                                              \
      const int col_ = (off_ & 127) ^ ((row_ & 7) << 4);                       \
      const char* gk_ = (const char*)k_ws +                                    \
          ((size_t)bh * 2048 + (size_t)(J0N) + row_) * 128 + col_;             \
      const char* gv_ = (const char*)v_t +                                     \
          ((size_t)bh * 64 + row_) * 4096 + (size_t)(J0N) * 2 + col_;          \
      gload16(gk_, (char*)&Ks[BUFD][0][0] + ch_ * 1024);                       \
      gload16(gv_, (char*)&Vs[BUFD][0][0] + ch_ * 1024);                       \
    }                                                                          \
  } while (0)

#define ATTN_LOADB(BV, J0N)                                                    \
  do {                                                                         \
    _Pragma("unroll") for (int nt_ = 0; nt_ < 4; ++nt_)                        \
        _Pragma("unroll") for (int r_ = 0; r_ < 4; ++r_)                       \
            BV[nt_][r_] = brow[r_][(J0N) + nt_ * 16];                          \
  } while (0)

#define ATTN_BODY(BUFC, BVC, BVN, J0N, DONEXT)                                 \
  do {                                                                         \
    if (DONEXT) {                                                              \
      ATTN_STAGE((BUFC) ^ 1, (J0N));                                           \
      ATTN_LOADB(BVN, (J0N));                                                  \
    }                                                                          \
    f32x4 S_[4];                                                               \
    __builtin_amdgcn_s_setprio(1);                                             \
    _Pragma("unroll") for (int nt_ = 0; nt_ < 4; ++nt_) {                      \
      const char* kb_ = (const char*)&Ks[BUFC][0][0] + (nt_ * 16 + l15) * 128; \
      bf16x8 k0_ = *(const bf16x8*)(kb_ + cs);                                 \
      bf16x8 k1_ = *(const bf16x8*)(kb_ + (cs ^ 64));                          \
      f32x4 s_ = (f32x4){0.f, 0.f, 0.f, 0.f};                                  \
      s_ = MFMA16(aQ0, k0_, s_);                                               \
      s_ = MFMA16(aQ1, k1_, s_);                                               \
      S_[nt_] = s_;                                                            \
    }                                                                          \
    __builtin_amdgcn_s_setprio(0);                                             \
    _Pragma("unroll") for (int nt_ = 0; nt_ < 4; ++nt_) {                      \
      float p0_ = exp2f(fmaf(BVC[nt_][0], L2E, S_[nt_][0]));                   \
      float p1_ = exp2f(fmaf(BVC[nt_][1], L2E, S_[nt_][1]));                   \
      float p2_ = exp2f(fmaf(BVC[nt_][2], L2E, S_[nt_][2]));                   \
      float p3_ = exp2f(fmaf(BVC[nt_][3], L2E, S_[nt_][3]));                   \
      lsum[0] += p0_; lsum[1] += p1_; lsum[2] += p2_; lsum[3] += p3_;          \
      unsigned pk01_, pk23_;                                                   \
      asm("v_cvt_pk_bf16_f32 %0, %1, %2" : "=v"(pk01_) : "v"(p0_), "v"(p1_)); \
      asm("v_cvt_pk_bf16_f32 %0, %1, %2" : "=v"(pk23_) : "v"(p2_), "v"(p3_)); \
      char* pb_ = (char*)&Pw[w][0][0];                                         \
      const int c0_ = 2 * (nt_ * 16 + l15);                                    \
      const int q4_ = quad * 4;                                                \
      *(short*)(pb_ + (q4_ + 0) * 128 + (c0_ ^ (((q4_ + 0) & 7) << 4))) =      \
          (short)pk01_;                                                        \
      *(short*)(pb_ + (q4_ + 1) * 128 + (c0_ ^ (((q4_ + 1) & 7) << 4))) =      \
          (short)(pk01_ >> 16);                                                \
      *(short*)(pb_ + (q4_ + 2) * 128 + (c0_ ^ (((q4_ + 2) & 7) << 4))) =      \
          (short)pk23_;                                                        \
      *(short*)(pb_ + (q4_ + 3) * 128 + (c0_ ^ (((q4_ + 3) & 7) << 4))) =      \
          (short)(pk23_ >> 16);                                                \
    }                                                                          \
    {                                                                          \
      const char* pr_ = (const char*)&Pw[w][0][0] + l15 * 128;                 \
      bf16x8 aP0 = *(const bf16x8*)(pr_ + cs);                                 \
      bf16x8 aP1 = *(const bf16x8*)(pr_ + (cs ^ 64));                          \
      __builtin_amdgcn_s_setprio(1);                                           \
      _Pragma("unroll") for (int dt_ = 0; dt_ < 4; ++dt_) {                    \
        const char* vb_ =                                                      \
            (const char*)&Vs[BUFC][0][0] + (dt_ * 16 + l15) * 128;             \
        bf16x8 v0_ = *(const bf16x8*)(vb_ + cs);                               \
        bf16x8 v1_ = *(const bf16x8*)(vb_ + (cs ^ 64));                        \
        O[dt_] = MFMA16(aP0, v0_, O[dt_]);                                     \
        O[dt_] = MFMA16(aP1, v1_, O[dt_]);                                     \
      }                                                                        \
      __builtin_amdgcn_s_setprio(0);                                           \
    }                                                                          \
    __builtin_amdgcn_sched_barrier(0);                                         \
    asm volatile("s_waitcnt vmcnt(16)" ::: "memory");                          \
    __builtin_amdgcn_s_barrier();                                              \
    __builtin_amdgcn_sched_barrier(0);                                         \
  } while (0)

__global__ __launch_bounds__(256)
__attribute__((amdgpu_waves_per_eu(4, 4)))
void attn_kernel(const short* __restrict__ q_ws,
                 const short* __restrict__ k_ws,
                 const short* __restrict__ v_t,
                 const float* __restrict__ bias,
                 short* __restrict__ attnO) {
  __shared__ short Ks[2][64][64];   // [buf][key][d]   8KB x2
  __shared__ short Vs[2][64][64];   // [buf][d][seq]   8KB x2
  __shared__ short Pw[4][16][64];   // [wave][qrow][key] 8KB
  const int t = threadIdx.x;
  const int w = t >> 6, lane = t & 63, l15 = lane & 15, quad = lane >> 4;
  const int bid = blockIdx.x;
  const int h = bid & 7;                 // XCD = h under round-robin dispatch
  const int b = (bid >> 3) & 3;          // siblings 8 apart -> same XCD
  const int qb = bid >> 5;               // 0..31 (64-row q tiles)
  const int bh = b * 8 + h;
  const int q0 = qb * 64 + w * 16;
  const int cs = (quad * 16) ^ ((l15 & 7) << 4);   // shared LDS read swizzle

  const size_t qbase = ((size_t)bh * 2048 + q0 + l15) * 64 + quad * 8;
  bf16x8 aQ0 = *(const bf16x8*)(q_ws + qbase);
  bf16x8 aQ1 = *(const bf16x8*)(q_ws + qbase + 32);

  f32x4 O[4];
#pragma unroll
  for (int i = 0; i < 4; ++i) O[i] = (f32x4){0.f, 0.f, 0.f, 0.f};
  float lsum[4] = {0.f, 0.f, 0.f, 0.f};

  const float* brow[4];
#pragma unroll
  for (int r = 0; r < 4; ++r)
    brow[r] = bias + ((size_t)h * 2048 + q0 + quad * 4 + r) * 2048 + l15;

  float bvA[4][4], bvB[4][4];
  ATTN_STAGE(0, 0);
  ATTN_LOADB(bvA, 0);
  __syncthreads();

  for (int it = 0; it < 16; ++it) {
    const int j0 = it * 128;
    ATTN_BODY(0, bvA, bvB, j0 + 64, 1);
    ATTN_BODY(1, bvB, bvA, j0 + 128, (it < 15));
  }

  // one 16-lane reduction of l at the very end
#pragma unroll
  for (int off = 1; off <= 8; off <<= 1)
#pragma unroll
    for (int r = 0; r < 4; ++r) lsum[r] += __shfl_xor(lsum[r], off);
#pragma unroll
  for (int r = 0; r < 4; ++r) lsum[r] = 1.f / lsum[r];
#pragma unroll
  for (int dt = 0; dt < 4; ++dt)
#pragma unroll
    for (int r = 0; r < 4; ++r) {
      size_t row = (size_t)b * 2048 + q0 + quad * 4 + r;
      attnO[row * 512 + h * 64 + dt * 16 + l15] = f2bf(O[dt][r] * lsum[r]);
    }
#undef ATTN_STAGE
#undef ATTN_LOADB
#undef ATTN_BODY
}

// ---------------- K3: output projection (fp32 out) ----------------

__global__ __launch_bounds__(256) void gemm_out(const short* __restrict__ A,
                                                const short* __restrict__ BT,
                                                float* __restrict__ out) {
  __shared__ short As[2][128][32];
  __shared__ short Bs[2][128][32];
  const int t = threadIdx.x;
  const int w = t >> 6, lane = t & 63, l15 = lane & 15, quad = lane >> 4;
  const int wm = (w & 1) * 64, wn = (w >> 1) * 64;
  const int m0 = blockIdx.y * 128, n0 = blockIdx.x * 128;
  f32x4 acc[4][4];
#pragma unroll
  for (int i = 0; i < 4; ++i)
#pragma unroll
    for (int j = 0; j < 4; ++j) acc[i][j] = (f32x4){0.f, 0.f, 0.f, 0.f};

  gemm128_async(A, BT, m0, n0, (char*)&As[0][0][0], (char*)&Bs[0][0][0], acc);

#pragma unroll
  for (int i = 0; i < 4; ++i)
#pragma unroll
    for (int j = 0; j < 4; ++j)
#pragma unroll
      for (int r = 0; r < 4; ++r)
        out[(size_t)(m0 + wm + i * 16 + quad * 4 + r) * 512 + n0 + wn + j * 16 + l15] =
            acc[i][j][r];
}

// ---------------- launch ----------------

extern "C" void kernel_launch(void* const* d_in, const int* in_sizes, int n_in,
                              void* d_out, int out_size, void* d_ws, size_t ws_size,
                              hipStream_t stream) {
  (void)in_sizes; (void)n_in; (void)out_size; (void)ws_size;
  const float* x        = (const float*)d_in[0];
  const float* pos_bias = (const float*)d_in[1];
  const float* w_qkv    = (const float*)d_in[2];
  const float* w_out    = (const float*)d_in[3];
  float* out = (float*)d_out;

  short* ws = (short*)d_ws;
  const size_t SEG = (size_t)32 * 2048 * 64;   // 4.19M elems
  short* q_ws  = ws;
  short* k_ws  = q_ws + SEG;
  short* v_t   = k_ws + SEG;
  short* attnO = v_t + SEG;
  short* xbf   = attnO + SEG;                  // [8192][512]
  short* wqkvT = xbf + SEG;                    // [1536][512]
  short* woutT = wqkvT + (size_t)1536 * 512;   // [512][512]

  prep<<<2304, 256, 0, stream>>>(x, w_qkv, w_out, xbf, wqkvT, woutT);
  gemm_qkv<<<dim3(12, 64), 256, 0, stream>>>(xbf, wqkvT, q_ws, k_ws, v_t);
  attn_kernel<<<1024, 256, 0, stream>>>(q_ws, k_ws, v_t, pos_bias, attnO);
  gemm_out<<<dim3(4, 64), 256, 0, stream>>>(attnO, woutT, out);
}